// Round 7
// baseline (89.153 us; speedup 1.0000x reference)
//
#include <hip/hip_runtime.h>
#include <math.h>

#define IMG 128
#define NPIX (IMG * IMG)
#define NF 1024
#define NEAR_Z 0.1f
#define DY 0.015625f               // 2/IMG, exact power-of-2 step

struct AllViews { float m[4][12]; };  // per view: xax[3], yax[3], zax[3], eye[3]

__device__ __forceinline__ float fast_tanh(float x)
{
    float xc = fminf(fmaxf(x, -10.0f), 10.0f);
    float e = __expf(2.0f * xc);
    return __fdividef(e - 1.0f, e + 1.0f);
}

// Fully fused: block = (view, 2-row strip), 256 threads, 1 px/thread.
// Phase 1: build all 1024 face planes+bbox into LDS (4 faces/thread).
// Phase 2: per-wave ballot cull (exact row-y + wave x-span) per 64-face word.
// Phase 3: ctz-scan survivors (broadcast LDS reads), winner in registers.
// Phase 4: inline shade (trilinear tanh texture) + loss, block partial sum.
__global__ __launch_bounds__(256) void render(
    const float* __restrict__ verts, const int* __restrict__ faces,
    const float* __restrict__ tex, const float* __restrict__ refs,
    float* __restrict__ partial, AllViews vc, float W)
{
    __shared__ float4 P0[NF];   // a1x a1y b1 a2x
    __shared__ float4 P1[NF];   // a2y b2 z0 g1
    __shared__ float  G2[NF];
    __shared__ float4 BB[NF];   // xmin xmax ymin ymax
    __shared__ float wsum[4];

    int bid = blockIdx.x;
    int view  = bid >> 6;          // 64 strips per view
    int strip = bid & 63;          // 2 rows each
    int tid  = threadIdx.x;
    int wave = tid >> 6, lane = tid & 63;
    const float* M = vc.m[view];

    // ---- Phase 1: build face records (planes + bbox) ----
#pragma unroll
    for (int b = 0; b < 4; ++b) {
        int f = b * 256 + tid;
        float proj[3][3];
#pragma unroll
        for (int k = 0; k < 3; ++k) {
            int vi = faces[f * 3 + k];
            float px = verts[vi * 3 + 0] - M[9];
            float py = verts[vi * 3 + 1] - M[10];
            float pz = verts[vi * 3 + 2] - M[11];
            float x = M[0] * px + M[1] * py + M[2] * pz;
            float y = M[3] * px + M[4] * py + M[5] * pz;
            float z = M[6] * px + M[7] * py + M[8] * pz;
            proj[k][0] = x / (z * W);
            proj[k][1] = y / (z * W);
            proj[k][2] = z;
        }
        float v0x = proj[0][0], v0y = proj[0][1];
        float e1x = proj[1][0] - v0x, e1y = proj[1][1] - v0y;
        float e2x = proj[2][0] - v0x, e2y = proj[2][1] - v0y;
        float det = e1x * e2y - e1y * e2x;
        bool ok = fabsf(det) > 1e-8f;
        float inv = ok ? 1.0f / det : 0.0f;
        float a1x = e2y * inv, a1y = -e2x * inv;
        float b1 = -(a1x * v0x + a1y * v0y);
        float a2x = -e1y * inv, a2y = e1x * inv;
        float b2 = -(a2x * v0x + a2y * v0y);
        float z0 = ok ? proj[0][2] : 0.0f;   // !ok -> depth 0 < NEAR -> invisible
        float g1 = proj[1][2] - proj[0][2];
        float g2 = proj[2][2] - proj[0][2];
        P0[f] = make_float4(a1x, a1y, b1, a2x);
        P1[f] = make_float4(a2y, b2, z0, g1);
        G2[f] = g2;
        float xmin = INFINITY, xmax = -INFINITY, ymin = INFINITY, ymax = -INFINITY;
        if (ok) {
            xmin = fminf(fminf(proj[0][0], proj[1][0]), proj[2][0]);
            xmax = fmaxf(fmaxf(proj[0][0], proj[1][0]), proj[2][0]);
            ymin = fminf(fminf(proj[0][1], proj[1][1]), proj[2][1]);
            ymax = fmaxf(fmaxf(proj[0][1], proj[1][1]), proj[2][1]);
        }
        BB[f] = make_float4(xmin, xmax, ymin, ymax);
    }
    __syncthreads();

    // ---- Phase 2+3: cull + scan. wave -> (row, col-half); lane -> col ----
    int row = strip * 2 + (wave >> 1);
    int colh = wave & 1;
    int col = colh * 64 + lane;
    float sx = (col + 0.5f) * DY - 1.0f;
    float sy = 1.0f - (row + 0.5f) * DY;
    float wx0 = (colh * 64 + 0.5f) * DY - 1.0f;   // wave's x-span (exact)
    float wx1 = wx0 + 63.0f * DY;

    float best = INFINITY;
    int bf = 0;

    for (int word = 0; word < 16; ++word) {
        float4 bb = BB[word * 64 + lane];
        bool inter = (bb.z <= sy) && (bb.w >= sy) &&   // y: exact row
                     (bb.x <= wx1) && (bb.y >= wx0);   // x: wave span
        unsigned long long m = __ballot(inter);
        int fbase = word * 64;
        while (m) {
            int f = fbase + (int)__builtin_ctzll(m);
            m &= m - 1;
            float4 q0 = P0[f];          // broadcast reads
            float4 q1 = P1[f];
            float g2  = G2[f];
            float w1 = fmaf(q0.x, sx, fmaf(q0.y, sy, q0.z));
            float w2 = fmaf(q0.w, sx, fmaf(q1.x, sy, q1.y));
            float dep = fmaf(w2, g2, fmaf(w1, q1.w, q1.z));
            bool vis = (fminf(w1, w2) >= 0.0f) && (w1 + w2 <= 1.0f) &&
                       (dep > NEAR_Z);
            bool take = vis && (dep < best);   // strict <: lowest f wins
            best = take ? dep : best;
            bf   = take ? f : bf;
        }
    }

    // ---- Phase 4: shade + loss ----
    float ref = refs[view * NPIX + row * IMG + col];
    float lossv;
    if (best < INFINITY) {
        float4 q0 = P0[bf];
        float4 q1 = P1[bf];
        float w1 = fmaf(q0.x, sx, fmaf(q0.y, sy, q0.z));
        float w2 = fmaf(q0.w, sx, fmaf(q1.x, sy, q1.y));
        float w0 = 1.0f - w1 - w2;
        float cx = fminf(fmaxf(w0, 0.0f), 1.0f) * 3.0f;
        float cy = fminf(fmaxf(w1, 0.0f), 1.0f) * 3.0f;
        float cz = fminf(fmaxf(w2, 0.0f), 1.0f) * 3.0f;
        int ix = min(max((int)floorf(cx), 0), 2);
        int iy = min(max((int)floorf(cy), 0), 2);
        int iz = min(max((int)floorf(cz), 0), 2);
        float fx = cx - (float)ix, fy = cy - (float)iy, fz = cz - (float)iz;

        const float* T = tex + (size_t)bf * 192;   // 4*4*4*3
        float c0 = 0.0f, c1 = 0.0f, c2 = 0.0f;
#pragma unroll
        for (int dxi = 0; dxi < 2; ++dxi)
#pragma unroll
            for (int dyi = 0; dyi < 2; ++dyi)
#pragma unroll
                for (int dzi = 0; dzi < 2; ++dzi) {
                    float w = (dxi ? fx : 1.0f - fx) *
                              (dyi ? fy : 1.0f - fy) *
                              (dzi ? fz : 1.0f - fz);
                    int base = (((ix + dxi) * 4 + (iy + dyi)) * 4 + (iz + dzi)) * 3;
                    c0 += w * fast_tanh(T[base + 0]);
                    c1 += w * fast_tanh(T[base + 1]);
                    c2 += w * fast_tanh(T[base + 2]);
                }
        float d0 = c0 - ref, d1 = c1 - ref, d2 = c2 - ref;
        lossv = d0 * d0 + d1 * d1 + d2 * d2;
    } else {
        lossv = 3.0f * ref * ref;
    }

    for (int off = 32; off; off >>= 1) lossv += __shfl_down(lossv, off);
    if ((tid & 63) == 0) wsum[tid >> 6] = lossv;
    __syncthreads();
    if (tid == 0) partial[bid] = wsum[0] + wsum[1] + wsum[2] + wsum[3];
}

// Single block: fixed-order sum of 256 partials -> scalar loss.
__global__ __launch_bounds__(256) void final_reduce(
    const float* __restrict__ partial, float* __restrict__ out)
{
    __shared__ float wsum[4];
    int tid = threadIdx.x;
    float v = partial[tid];
    for (int off = 32; off; off >>= 1) v += __shfl_down(v, off);
    if ((tid & 63) == 0) wsum[tid >> 6] = v;
    __syncthreads();
    if (tid == 0) out[0] = wsum[0] + wsum[1] + wsum[2] + wsum[3];
}

static void make_view(double dist, double elev, double azim, float* M)
{
    double e = elev * M_PI / 180.0, a = azim * M_PI / 180.0;
    float ex = (float)(dist * cos(e) * sin(a));
    float ey = (float)(dist * sin(e));
    float ez = (float)(-dist * cos(e) * cos(a));
    float zx = -ex, zy = -ey, zz = -ez;
    float n = sqrtf(zx * zx + zy * zy + zz * zz);
    zx /= n; zy /= n; zz /= n;
    float xx = zz, xy = 0.0f, xz = -zx;
    n = sqrtf(xx * xx + xy * xy + xz * xz);
    xx /= n; xy /= n; xz /= n;
    float yx = zy * xz - zz * xy;
    float yy = zz * xx - zx * xz;
    float yz = zx * xy - zy * xx;
    n = sqrtf(yx * yx + yy * yy + yz * yz);
    yx /= n; yy /= n; yz /= n;
    M[0] = xx; M[1] = xy; M[2] = xz;
    M[3] = yx; M[4] = yy; M[5] = yz;
    M[6] = zx; M[7] = zy; M[8] = zz;
    M[9] = ex; M[10] = ey; M[11] = ez;
}

extern "C" void kernel_launch(void* const* d_in, const int* in_sizes, int n_in,
                              void* d_out, int out_size, void* d_ws, size_t ws_size,
                              hipStream_t stream)
{
    const float* verts = (const float*)d_in[0];
    const int*   faces = (const int*)d_in[1];
    const float* tex   = (const float*)d_in[2];
    const float* refs  = (const float*)d_in[3];
    float* out = (float*)d_out;
    float* partial = (float*)d_ws;    // 256 floats, all written every call

    AllViews vc;
    const double V[4][3] = {{2.83, 45.0, 0.0}, {2.0, 0.0, 90.0},
                            {3.46, 45.0, 45.0}, {3.0, 0.0, 0.0}};
    for (int i = 0; i < 4; ++i) make_view(V[i][0], V[i][1], V[i][2], vc.m[i]);
    float W = (float)tan(M_PI / 6.0);

    render<<<256, 256, 0, stream>>>(verts, faces, tex, refs, partial, vc, W);
    final_reduce<<<1, 256, 0, stream>>>(partial, out);
}

// Round 8
// 44.470 us; speedup vs baseline: 2.0048x; 2.0048x over previous
//
#include <hip/hip_runtime.h>
#include <hip/hip_fp16.h>
#include <math.h>

#define IMG 128
#define NPIX (IMG * IMG)
#define NF 1024
#define NCHUNK 4
#define CHF 256                    // faces per chunk
#define NEAR_Z 0.1f
#define DY 0.015625f               // 2/IMG, exact power-of-2 step

struct AllViews { float m[4][12]; };  // per view: xax[3], yax[3], zax[3], eye[3]

__device__ __forceinline__ float fast_tanh(float x)
{
    float xc = fminf(fmaxf(x, -10.0f), 10.0f);
    float e = __expf(2.0f * xc);
    return __fdividef(e - 1.0f, e + 1.0f);
}

// Record (3 x float4):
//   Q0 = (a1x, a1y, b1, ddx)   w1  = a1.p + b1
//   Q1 = (a2x, a2y, b2, ddy)   w2  = a2.p + b2
//   Q2 = (dc, packed_x_bbox_f16, packed_y_bbox_f16, 0)  dep = dd.p + dc
// !ok -> all-zero planes -> dep = 0 < NEAR -> invisible (matches ref `ok`).
// f16 bbox is conservative (rd/ru rounding) -> cull is an exact superset.
__global__ void precompute(const float* __restrict__ verts,
                           const int* __restrict__ faces,
                           float4* __restrict__ fd,
                           unsigned int* __restrict__ counter,
                           AllViews vc, float W)
{
    int t = blockIdx.x * blockDim.x + threadIdx.x;
    if (t == 0) *counter = 0;         // reset for shade's last-block pattern
    if (t >= 4 * NF) return;
    int view = t >> 10, f = t & (NF - 1);
    const float* M = vc.m[view];

    float proj[3][3];
#pragma unroll
    for (int k = 0; k < 3; ++k) {
        int vi = faces[f * 3 + k];
        float px = verts[vi * 3 + 0] - M[9];
        float py = verts[vi * 3 + 1] - M[10];
        float pz = verts[vi * 3 + 2] - M[11];
        float x = M[0] * px + M[1] * py + M[2] * pz;
        float y = M[3] * px + M[4] * py + M[5] * pz;
        float z = M[6] * px + M[7] * py + M[8] * pz;
        proj[k][0] = x / (z * W);
        proj[k][1] = y / (z * W);
        proj[k][2] = z;
    }
    float v0x = proj[0][0], v0y = proj[0][1];
    float e1x = proj[1][0] - v0x, e1y = proj[1][1] - v0y;
    float e2x = proj[2][0] - v0x, e2y = proj[2][1] - v0y;
    float det = e1x * e2y - e1y * e2x;
    bool ok = fabsf(det) > 1e-8f;
    float inv = ok ? 1.0f / det : 0.0f;
    float a1x = e2y * inv, a1y = -e2x * inv;
    float b1 = -(a1x * v0x + a1y * v0y);
    float a2x = -e1y * inv, a2y = e1x * inv;
    float b2 = -(a2x * v0x + a2y * v0y);
    float z0 = ok ? proj[0][2] : 0.0f;
    float g1 = proj[1][2] - proj[0][2];
    float g2 = proj[2][2] - proj[0][2];
    // depth plane: dep = ddx*sx + ddy*sy + dc   (zero when !ok)
    float ddx = ok ? (g1 * a1x + g2 * a2x) : 0.0f;
    float ddy = ok ? (g1 * a1y + g2 * a2y) : 0.0f;
    float dc  = ok ? (z0 + g1 * b1 + g2 * b2) : 0.0f;

    float xmin = INFINITY, xmax = -INFINITY, ymin = INFINITY, ymax = -INFINITY;
    if (ok) {
        xmin = fminf(fminf(proj[0][0], proj[1][0]), proj[2][0]);
        xmax = fmaxf(fmaxf(proj[0][0], proj[1][0]), proj[2][0]);
        ymin = fminf(fminf(proj[0][1], proj[1][1]), proj[2][1]);
        ymax = fmaxf(fmaxf(proj[0][1], proj[1][1]), proj[2][1]);
    }
    // conservative f16: min rounded down, max rounded up
    __half2 hx = __halves2half2(__float2half_rd(xmin), __float2half_ru(xmax));
    __half2 hy = __halves2half2(__float2half_rd(ymin), __float2half_ru(ymax));

    float4* o = fd + (size_t)t * 3;
    o[0] = make_float4(a1x, a1y, b1, ddx);
    o[1] = make_float4(a2x, a2y, b2, ddy);
    o[2] = make_float4(dc, __uint_as_float(*(unsigned int*)&hx),
                           __uint_as_float(*(unsigned int*)&hy), 0.0f);
}

// Block = (view, 16x16 px tile, 256-face chunk). Stage chunk (12 KB) with
// coalesced float4 loads. Wave = 8x8 px sub-tile: ballot 2D bbox cull per
// 64-face word, compact survivors to a per-wave LDS list, then a DENSE
// counted loop (pipelineable) evaluates planes. 1 px/thread. No atomics.
__global__ __launch_bounds__(256, 4) void raster(
    const float4* __restrict__ fd,
    unsigned long long* __restrict__ keys)
{
    __shared__ float4 lds4[CHF * 3];           // 12 KB
    __shared__ unsigned short list[4][CHF];    // 2 KB, per-wave survivor list

    int bid = blockIdx.x;
    int view  = bid >> 8;          // 256 blocks per view
    int b     = bid & 255;
    int chunk = b & (NCHUNK - 1);
    int tile  = b >> 2;            // 0..63 -> 16x16 px tile
    int tid  = threadIdx.x;
    int wave = tid >> 6, lane = tid & 63;

    const float4* src = fd + (size_t)(view * NF + chunk * CHF) * 3;
    for (int i = tid; i < CHF * 3; i += 256) lds4[i] = src[i];
    __syncthreads();

    // wave -> 8x8 sub-tile origin; lane -> pixel
    int tr = (tile >> 3) * 16 + (wave >> 1) * 8;   // tile row 0..120
    int tc = (tile & 7) * 16 + (wave & 1) * 8;     // tile col 0..120
    int r  = tr + (lane >> 3);
    int c  = tc + (lane & 7);
    float sx = (c + 0.5f) * DY - 1.0f;
    float sy = 1.0f - (r + 0.5f) * DY;
    // wave spans: x in [cx0,cx1], y in [syLo,syHi] (exact fp32 values)
    float cx0 = (tc + 0.5f) * DY - 1.0f;
    float cx1 = (tc + 7.5f) * DY - 1.0f;
    float syHi = 1.0f - (tr + 0.5f) * DY;
    float syLo = 1.0f - (tr + 7.5f) * DY;

    // ---- ballot cull + compaction (4 words of 64 faces) ----
    int cnt = 0;
#pragma unroll
    for (int word = 0; word < 4; ++word) {
        int fi = word * 64 + lane;
        float4 q2 = lds4[fi * 3 + 2];
        unsigned int bxu = __float_as_uint(q2.y);
        unsigned int byu = __float_as_uint(q2.z);
        __half2 hx = *(__half2*)&bxu;   // (xmin, xmax)
        __half2 hy = *(__half2*)&byu;   // (ymin, ymax)
        float xmin = __low2float(hx),  xmax = __high2float(hx);
        float ymin = __low2float(hy),  ymax = __high2float(hy);
        bool inter = (xmin <= cx1) && (xmax >= cx0) &&
                     (ymin <= syHi) && (ymax >= syLo);
        unsigned long long m = __ballot(inter);
        int prefix = __popcll(m & ((1ull << lane) - 1ull));
        if (inter) list[wave][cnt + prefix] = (unsigned short)fi;
        cnt += (int)__popcll(m);
    }

    // ---- dense scan over survivors (ascending face order preserved) ----
    float best = INFINITY;
    int bf = 0;
    const float* ldsf = (const float*)lds4;
#pragma unroll 2
    for (int i = 0; i < cnt; ++i) {
        int f = list[wave][i];              // broadcast read
        float4 q0 = lds4[f * 3 + 0];
        float4 q1 = lds4[f * 3 + 1];
        float dc  = ldsf[f * 12 + 8];
        float w1  = fmaf(q0.x, sx, fmaf(q0.y, sy, q0.z));
        float w2  = fmaf(q1.x, sx, fmaf(q1.y, sy, q1.z));
        float dep = fmaf(q0.w, sx, fmaf(q1.w, sy, dc));
        bool vis  = (fminf(w1, w2) >= 0.0f) && (w1 + w2 <= 1.0f) &&
                    (dep > NEAR_Z);
        bool take = vis && (dep < best);    // strict <: lowest f wins
        best = take ? dep : best;
        bf   = take ? f : bf;
    }

    unsigned long long key =
        ((unsigned long long)__float_as_uint(best) << 32) |
        (unsigned int)(chunk * CHF + bf);
    keys[((size_t)(view * NCHUNK + chunk) << 14) + r * IMG + c] = key;
}

// One thread per (view,pixel): min over 4 chunk keys, winner planes from fd,
// trilinear tanh texture, loss; last block does fixed-order final reduce.
__global__ __launch_bounds__(256) void shade_loss(
    const float4* __restrict__ fd,
    const unsigned long long* __restrict__ keys,
    const float* __restrict__ tex,
    const float* __restrict__ refs,
    float* __restrict__ partial, unsigned int* __restrict__ counter,
    float* __restrict__ out)
{
    __shared__ float wsum[4];
    __shared__ bool last;
    int tid = threadIdx.x;
    int t = blockIdx.x * 256 + tid;
    int view = t >> 14, p = t & (NPIX - 1);
    int row = p >> 7, col = p & 127;
    float sx = (col + 0.5f) * DY - 1.0f;
    float sy = 1.0f - (row + 0.5f) * DY;

    const unsigned long long* kb = keys + ((size_t)(view * NCHUNK) << 14) + p;
    unsigned long long key = ~0ULL;
#pragma unroll
    for (int c = 0; c < NCHUNK; ++c) {
        unsigned long long k = kb[(size_t)c << 14];
        key = (k < key) ? k : key;
    }

    bool hit = (unsigned int)(key >> 32) < 0x7f800000u;
    float ref = refs[t];
    float lossv;
    if (hit) {
        int f = (int)(key & 0xffffffffu);
        const float4* Q = fd + (size_t)(view * NF + f) * 3;
        float4 q0 = Q[0];
        float4 q1 = Q[1];
        float w1 = fmaf(q0.x, sx, fmaf(q0.y, sy, q0.z));
        float w2 = fmaf(q1.x, sx, fmaf(q1.y, sy, q1.z));
        float w0 = 1.0f - w1 - w2;
        float cx = fminf(fmaxf(w0, 0.0f), 1.0f) * 3.0f;
        float cy = fminf(fmaxf(w1, 0.0f), 1.0f) * 3.0f;
        float cz = fminf(fmaxf(w2, 0.0f), 1.0f) * 3.0f;
        int ix = min(max((int)floorf(cx), 0), 2);
        int iy = min(max((int)floorf(cy), 0), 2);
        int iz = min(max((int)floorf(cz), 0), 2);
        float fx = cx - (float)ix, fy = cy - (float)iy, fz = cz - (float)iz;

        const float* T = tex + (size_t)f * 192;   // 4*4*4*3
        float c0 = 0.0f, c1 = 0.0f, c2 = 0.0f;
#pragma unroll
        for (int dxi = 0; dxi < 2; ++dxi)
#pragma unroll
            for (int dyi = 0; dyi < 2; ++dyi)
#pragma unroll
                for (int dzi = 0; dzi < 2; ++dzi) {
                    float w = (dxi ? fx : 1.0f - fx) *
                              (dyi ? fy : 1.0f - fy) *
                              (dzi ? fz : 1.0f - fz);
                    int base = (((ix + dxi) * 4 + (iy + dyi)) * 4 + (iz + dzi)) * 3;
                    c0 += w * fast_tanh(T[base + 0]);
                    c1 += w * fast_tanh(T[base + 1]);
                    c2 += w * fast_tanh(T[base + 2]);
                }
        float d0 = c0 - ref, d1 = c1 - ref, d2 = c2 - ref;
        lossv = d0 * d0 + d1 * d1 + d2 * d2;
    } else {
        lossv = 3.0f * ref * ref;
    }

    for (int off = 32; off; off >>= 1) lossv += __shfl_down(lossv, off);
    if ((tid & 63) == 0) wsum[tid >> 6] = lossv;
    __syncthreads();
    if (tid == 0) {
        partial[blockIdx.x] = wsum[0] + wsum[1] + wsum[2] + wsum[3];
        __threadfence();
        unsigned int old = atomicAdd(counter, 1);
        last = (old == (unsigned int)(gridDim.x - 1));
    }
    __syncthreads();
    if (last) {                       // fixed-order sum -> deterministic
        __threadfence();
        float v = partial[tid];
        for (int off = 32; off; off >>= 1) v += __shfl_down(v, off);
        if ((tid & 63) == 0) wsum[tid >> 6] = v;
        __syncthreads();
        if (tid == 0) out[0] = wsum[0] + wsum[1] + wsum[2] + wsum[3];
    }
}

static void make_view(double dist, double elev, double azim, float* M)
{
    double e = elev * M_PI / 180.0, a = azim * M_PI / 180.0;
    float ex = (float)(dist * cos(e) * sin(a));
    float ey = (float)(dist * sin(e));
    float ez = (float)(-dist * cos(e) * cos(a));
    float zx = -ex, zy = -ey, zz = -ez;
    float n = sqrtf(zx * zx + zy * zy + zz * zz);
    zx /= n; zy /= n; zz /= n;
    float xx = zz, xy = 0.0f, xz = -zx;
    n = sqrtf(xx * xx + xy * xy + xz * xz);
    xx /= n; xy /= n; xz /= n;
    float yx = zy * xz - zz * xy;
    float yy = zz * xx - zx * xz;
    float yz = zx * xy - zy * xx;
    n = sqrtf(yx * yx + yy * yy + yz * yz);
    yx /= n; yy /= n; yz /= n;
    M[0] = xx; M[1] = xy; M[2] = xz;
    M[3] = yx; M[4] = yy; M[5] = yz;
    M[6] = zx; M[7] = zy; M[8] = zz;
    M[9] = ex; M[10] = ey; M[11] = ez;
}

extern "C" void kernel_launch(void* const* d_in, const int* in_sizes, int n_in,
                              void* d_out, int out_size, void* d_ws, size_t ws_size,
                              hipStream_t stream)
{
    const float* verts = (const float*)d_in[0];
    const int*   faces = (const int*)d_in[1];
    const float* tex   = (const float*)d_in[2];
    const float* refs  = (const float*)d_in[3];
    float* out = (float*)d_out;

    char* ws = (char*)d_ws;
    float4* fd = (float4*)ws;                             // 4*1024*48B = 192 KB
    ws += (size_t)4 * NF * 3 * sizeof(float4);
    unsigned long long* keys = (unsigned long long*)ws;   // 4*4*16384*8 = 2 MB
    ws += (size_t)4 * NCHUNK * NPIX * sizeof(unsigned long long);
    float* partial = (float*)ws;                          // 256 floats
    ws += 256 * sizeof(float);
    unsigned int* counter = (unsigned int*)ws;            // 4 B

    AllViews vc;
    const double V[4][3] = {{2.83, 45.0, 0.0}, {2.0, 0.0, 90.0},
                            {3.46, 45.0, 45.0}, {3.0, 0.0, 0.0}};
    for (int i = 0; i < 4; ++i) make_view(V[i][0], V[i][1], V[i][2], vc.m[i]);
    float W = (float)tan(M_PI / 6.0);

    precompute<<<16, 256, 0, stream>>>(verts, faces, fd, counter, vc, W);
    raster<<<1024, 256, 0, stream>>>(fd, keys);
    shade_loss<<<256, 256, 0, stream>>>(fd, keys, tex, refs,
                                        partial, counter, out);
}